// Round 6
// baseline (1517.240 us; speedup 1.0000x reference)
//
#include <hip/hip_runtime.h>

#define HH 64
#define WW 64
#define TT 100
#define CO 8
#define KS 6
#define LP 2
#define TS 16
#define HS 21          // TS + KS - 1
#define NS 441         // halo sites
#define NG 7           // max float4 per chunk (28 t)
#define NSLOT 3087     // NS * NG
#define NTHR 512

__device__ __forceinline__ float stepu(float u, float s, float th, float wx) {
    // u = (u - s*th) + wx  -- exact reference association, no contraction
    return __fadd_rn(__fsub_rn(u, __fmul_rn(s, th)), wx);
}

#define FMA4(ACC, WD) \
    ACC.x = __fmaf_rn((WD), xv.x, ACC.x); \
    ACC.y = __fmaf_rn((WD), xv.y, ACC.y); \
    ACC.z = __fmaf_rn((WD), xv.z, ACC.z); \
    ACC.w = __fmaf_rn((WD), xv.w, ACC.w);

#define SCAN4(J) { \
    float u = ut[J], s = sprev[J]; unsigned m = 0u; \
    u = stepu(u, s, th, wx[J].x); s = (u > 0.f) ? 1.f : 0.f; m |= (u > 0.f) ? 1u : 0u; \
    u = stepu(u, s, th, wx[J].y); s = (u > 0.f) ? 1.f : 0.f; m |= (u > 0.f) ? 2u : 0u; \
    u = stepu(u, s, th, wx[J].z); s = (u > 0.f) ? 1.f : 0.f; m |= (u > 0.f) ? 4u : 0u; \
    u = stepu(u, s, th, wx[J].w); s = (u > 0.f) ? 1.f : 0.f; m |= (u > 0.f) ? 8u : 0u; \
    ut[J] = u; sprev[J] = s; cb[J] |= m << sh; }

// stage one time-chunk into xs[tg*NS + site]; mask bit k = load-valid for slot k
__device__ __forceinline__ void stage_chunk(const float* __restrict__ xb,
                                            float4* __restrict__ xs,
                                            const int* __restrict__ offs,
                                            unsigned mask, int tid, int t0)
{
#pragma unroll
    for (int k = 0; k < 7; ++k) {
        const int i  = tid + (k << 9);
        const int ic = (k < 6) ? i : (tid < 15 ? i : 0);
        const int site = ic / 7;
        const int tg   = ic - site * 7;
        float4 v = make_float4(0.f, 0.f, 0.f, 0.f);
        if ((mask >> k) & 1u)
            v = *(const float4*)(xb + offs[k] + t0);
        if (k < 6 || tid < 15)          // guard: don't clobber slot 0
            xs[tg * NS + site] = v;
    }
}

template<int T0, int NGC>
__device__ __forceinline__ void compute_chunk(
    const float4* __restrict__ xs, const float4 (*__restrict__ wds4)[2],
    int rbase, int half, float th, float* ut, float* sprev, unsigned* bw)
{
    unsigned cb[4] = {0u, 0u, 0u, 0u};

#pragma unroll 1                 // rolled tg loop: ~5 KB body, I$-resident
    for (int tgl = 0; tgl < NGC; ++tgl) {
        const float4* xrow = xs + tgl * NS + rbase;
        float4 wx[4];
#pragma unroll
        for (int j = 0; j < 4; ++j) wx[j] = make_float4(0.f, 0.f, 0.f, 0.f);
#pragma unroll
        for (int kh = 0; kh < KS; ++kh) {
#pragma unroll
            for (int kw = 0; kw < KS; ++kw) {
                const float4 xv = xrow[kh * HS + kw];
                const float4 wv = wds4[kh * KS + kw][half];   // uniform broadcast
                FMA4(wx[0], wv.x); FMA4(wx[1], wv.y);
                FMA4(wx[2], wv.z); FMA4(wx[3], wv.w);
            }
        }
        const int sh = tgl * 4;
        SCAN4(0); SCAN4(1); SCAN4(2); SCAN4(3);
    }

    constexpr int W0 = T0 / 32;
    constexpr int S  = T0 % 32;
#pragma unroll
    for (int j = 0; j < 4; ++j) {
        bw[j * 4 + W0] |= cb[j] << S;
        if constexpr (S + NGC * 4 > 32)
            bw[j * 4 + W0 + 1] |= cb[j] >> (32 - S);
    }
}

__global__ __launch_bounds__(512, 4)
void sconv2d_spike_kernel(const float* __restrict__ x,
                          const float* __restrict__ wgt,
                          const float* __restrict__ thresh,
                          float* __restrict__ out)
{
    __shared__ float4 xs[NSLOT];           // 49.4 KB chunk buffer / flush alias
    __shared__ float4 wds4[KS * KS][2];    // 1.2 KB [tap][co-half]

    const int tid = threadIdx.x;
    if (tid < KS * KS * CO) {
        const int co  = tid / (KS * KS);
        const int tap = tid - co * (KS * KS);
        ((float*)wds4)[tap * 8 + co] = wgt[tid];
    }
    const float th = thresh[0];

    // grid = 32 images x 16 tiles; 512 blocks x 512 thr = 2 blocks/CU exact
    const int blk  = blockIdx.x;
    const int b    = blk >> 4;
    const int tb   = blk & 15;
    const int h0   = (tb >> 2) << 4;
    const int w0   = (tb & 3) << 4;
    const int sid  = tid & 255;            // site 0..255
    const int half = tid >> 8;             // co-half: couts half*4..half*4+3
    const int r    = sid >> 4;
    const int c    = sid & 15;

    const float* xb = x + (size_t)b * (HH * WW * TT);

    // per-thread staging offsets (clamped coords) + validity masks
    int offs[7];
    unsigned vb_full = 0u, vb_last = 0u;
#pragma unroll
    for (int k = 0; k < 7; ++k) {
        const int i  = tid + (k << 9);
        const bool inr = i < NSLOT;
        const int ic = inr ? i : 0;
        const int site = ic / 7;
        const int tg   = ic - site * 7;
        const int hr = site / HS;
        const int hc = site - hr * HS;
        const int hh = h0 - LP + hr;
        const int ww = w0 - LP + hc;
        const bool valid = inr && ((unsigned)hh < (unsigned)HH)
                               && ((unsigned)ww < (unsigned)WW);
        const int hcl = hh < 0 ? 0 : (hh > HH - 1 ? HH - 1 : hh);
        const int wcl = ww < 0 ? 0 : (ww > WW - 1 ? WW - 1 : ww);
        offs[k] = (hcl * WW + wcl) * TT + tg * 4;
        if (valid)            vb_full |= 1u << k;
        if (valid && tg < 4)  vb_last |= 1u << k;   // last chunk: t<100 only
    }

    float ut[4], sprev[4];
    unsigned bw[16];
#pragma unroll
    for (int j = 0; j < 4; ++j) { ut[j] = 0.f; sprev[j] = 0.f; }
#pragma unroll
    for (int i = 0; i < 16; ++i) bw[i] = 0u;

    const int rbase = r * HS + c;

    stage_chunk(xb, xs, offs, vb_full, tid, 0);
    __syncthreads();
    compute_chunk< 0, 7>(xs, wds4, rbase, half, th, ut, sprev, bw);
    __syncthreads();

    stage_chunk(xb, xs, offs, vb_full, tid, 28);
    __syncthreads();
    compute_chunk<28, 7>(xs, wds4, rbase, half, th, ut, sprev, bw);
    __syncthreads();

    stage_chunk(xb, xs, offs, vb_full, tid, 56);
    __syncthreads();
    compute_chunk<56, 7>(xs, wds4, rbase, half, th, ut, sprev, bw);
    __syncthreads();

    stage_chunk(xb, xs, offs, vb_last, tid, 84);
    __syncthreads();
    compute_chunk<84, 4>(xs, wds4, rbase, half, th, ut, sprev, bw);
    __syncthreads();   // xs dead; alias as flush staging

    // ---- flush: stride-33 staging (bank-perfect), contiguous f4 stores ----
    unsigned* stg = (unsigned*)xs;          // 256*33 words = 33.8 KB <= 49.4 KB
#pragma unroll
    for (int w = 0; w < 16; ++w)
        stg[sid * 33 + half * 16 + w] = bw[w];
    __syncthreads();

    float* outb = out + (size_t)b * (CO * HH * WW * TT);
#pragma unroll 2
    for (int k = 0; k < 100; ++k) {
        const int idx = tid + (k << 9);       // 0..51199
        const int co  = idx / 6400;           // wave-uniform (6400 % 64 == 0)
        const int rem = idx - co * 6400;
        const int u   = rem / 25;             // site 0..255
        const int q   = rem - u * 25;
        const int tt  = q * 4;                // 0..96
        const unsigned bs =
            stg[u * 33 + (co >> 2) * 16 + (co & 3) * 4 + (tt >> 5)] >> (tt & 31);
        float4 v;
        v.x = (float)( bs        & 1u);
        v.y = (float)((bs >> 1)  & 1u);
        v.z = (float)((bs >> 2)  & 1u);
        v.w = (float)((bs >> 3)  & 1u);
        *(float4*)(outb + (((size_t)co * HH + (h0 + (u >> 4))) * WW
                           + (w0 + (u & 15))) * TT + tt) = v;
    }
}

extern "C" void kernel_launch(void* const* d_in, const int* in_sizes, int n_in,
                              void* d_out, int out_size, void* d_ws, size_t ws_size,
                              hipStream_t stream) {
    const float* x      = (const float*)d_in[0];
    const float* wgt    = (const float*)d_in[1];
    const float* thresh = (const float*)d_in[2];
    float* out = (float*)d_out;
    (void)d_ws; (void)ws_size;

    sconv2d_spike_kernel<<<dim3(32 * 16), dim3(NTHR), 0, stream>>>(x, wgt, thresh, out);
}

// Round 7
// 1419.139 us; speedup vs baseline: 1.0691x; 1.0691x over previous
//
#include <hip/hip_runtime.h>

#define HH 64
#define WW 64
#define TT 100
#define CO 8
#define COB 4                      // couts per block (split across 2 blocks)
#define KS 6
#define LP 2
#define HALO 21                    // 16 + 6 - 1
#define NSITE 441                  // 21*21
#define NGMAX 5

__device__ __forceinline__ float stepu(float u, float s, float th, float wx) {
    // u = (u - s*th) + wx  -- exact reference association, no contraction
    return __fadd_rn(__fsub_rn(u, __fmul_rn(s, th)), wx);
}

// Stage x[t0..t0+TC) halo into LDS, conv (kh-major sequential FMA, bit-exact
// vs np ref), scan; accumulate spike bits in registers (static indices only).
template<int T0, int TC>
__device__ __forceinline__ void process_chunk(
    const float* __restrict__ xb,
    float4* __restrict__ xs, const float (*wds)[CO],
    int tid, int r, int c, int h0, int w0, int co0, float th,
    float* ut, float* sprev, unsigned* bw /* COB*4 words, static idx */)
{
    constexpr int NG = TC / 4;

    for (int i = tid; i < NSITE * NG; i += 256) {
        const int s  = i / NG;
        const int tg = i - s * NG;
        const int hr = s / HALO;
        const int hc = s - hr * HALO;
        const int hh = h0 - LP + hr;
        const int ww = w0 - LP + hc;
        float4 v = make_float4(0.f, 0.f, 0.f, 0.f);
        if ((unsigned)hh < (unsigned)HH && (unsigned)ww < (unsigned)WW)
            v = *(const float4*)(xb + ((size_t)hh * WW + ww) * TT + T0 + tg * 4);
        xs[tg * NSITE + s] = v;
    }
    __syncthreads();

    unsigned cb[COB];
#pragma unroll
    for (int j = 0; j < COB; ++j) cb[j] = 0u;

    for (int tg = 0; tg < NG; ++tg) {
        float4 wx[COB];
#pragma unroll
        for (int j = 0; j < COB; ++j) wx[j] = make_float4(0.f, 0.f, 0.f, 0.f);
#pragma unroll
        for (int kh = 0; kh < KS; ++kh) {
#pragma unroll
            for (int kw = 0; kw < KS; ++kw) {
                const float4 xv = xs[tg * NSITE + (r + kh) * HALO + (c + kw)];
                const int tap = kh * KS + kw;
#pragma unroll
                for (int j = 0; j < COB; ++j) {
                    const float wd = wds[tap][co0 + j];
                    wx[j].x = __fmaf_rn(wd, xv.x, wx[j].x);
                    wx[j].y = __fmaf_rn(wd, xv.y, wx[j].y);
                    wx[j].z = __fmaf_rn(wd, xv.z, wx[j].z);
                    wx[j].w = __fmaf_rn(wd, xv.w, wx[j].w);
                }
            }
        }
        const int sh = tg * 4;
#pragma unroll
        for (int j = 0; j < COB; ++j) {
            float u = ut[j], s = sprev[j];
            unsigned m = 0u;
            u = stepu(u, s, th, wx[j].x); s = (u > 0.f) ? 1.f : 0.f; m |= (u > 0.f) ? 1u : 0u;
            u = stepu(u, s, th, wx[j].y); s = (u > 0.f) ? 1.f : 0.f; m |= (u > 0.f) ? 2u : 0u;
            u = stepu(u, s, th, wx[j].z); s = (u > 0.f) ? 1.f : 0.f; m |= (u > 0.f) ? 4u : 0u;
            u = stepu(u, s, th, wx[j].w); s = (u > 0.f) ? 1.f : 0.f; m |= (u > 0.f) ? 8u : 0u;
            ut[j] = u; sprev[j] = s;
            cb[j] |= m << sh;
        }
    }
    __syncthreads();   // compute done before next chunk overwrites xs

    constexpr int W0 = T0 / 32;
    constexpr int S  = T0 % 32;
#pragma unroll
    for (int j = 0; j < COB; ++j) {
        bw[j * 4 + W0] |= cb[j] << S;
        if constexpr (S + TC > 32)
            bw[j * 4 + W0 + 1] |= cb[j] >> ((32 - S) & 31);
    }
}

__global__ __launch_bounds__(256, 3)
void sconv2d_spike_kernel(const float* __restrict__ x,
                          const float* __restrict__ wgt,
                          const float* __restrict__ thresh,
                          float* __restrict__ out)
{
    __shared__ float4   xs[NGMAX * NSITE];    // 35.3 KB (20-t chunk)
    __shared__ float    wds[KS * KS][CO];     // 1.2 KB
    __shared__ unsigned stg[256][5];          // 5.1 KB (stride 5: conflict-free)
    // total 41.6 KB -> 3 blocks/CU (124.8/160 KB), 12 waves/CU

    const int tid = threadIdx.x;
    for (int i = tid; i < KS * KS * CO; i += 256) {
        const int co  = i / (KS * KS);
        const int tap = i - co * (KS * KS);
        wds[tap][co] = wgt[co * (KS * KS) + tap];
    }
    const float th = thresh[0];

    // grid = 32 images x 16 tiles x 2 co-halves
    const int blk  = blockIdx.x;
    const int b    = blk >> 5;
    const int rest = blk & 31;
    const int tb   = rest >> 1;
    const int co0  = (rest & 1) * COB;
    const int h0   = (tb >> 2) << 4;
    const int w0   = (tb & 3) << 4;
    const int r    = tid >> 4;
    const int c    = tid & 15;

    const float* xb   = x   + (size_t)b * (HH * WW * TT);
    float*       outb = out + (size_t)b * (CO * HH * WW * TT);

    float ut[COB], sprev[COB];
    unsigned bw[COB * 4];
#pragma unroll
    for (int j = 0; j < COB; ++j) { ut[j] = 0.f; sprev[j] = 0.f; }
#pragma unroll
    for (int i = 0; i < COB * 4; ++i) bw[i] = 0u;

    process_chunk< 0, 20>(xb, xs, wds, tid, r, c, h0, w0, co0, th, ut, sprev, bw);
    process_chunk<20, 20>(xb, xs, wds, tid, r, c, h0, w0, co0, th, ut, sprev, bw);
    process_chunk<40, 20>(xb, xs, wds, tid, r, c, h0, w0, co0, th, ut, sprev, bw);
    process_chunk<60, 20>(xb, xs, wds, tid, r, c, h0, w0, co0, th, ut, sprev, bw);
    process_chunk<80, 20>(xb, xs, wds, tid, r, c, h0, w0, co0, th, ut, sprev, bw);

    // ---- flush: per-co bit expansion, full-line coalesced float4 stores ----
#pragma unroll
    for (int j = 0; j < COB; ++j) {
        const int co = co0 + j;
        stg[tid][0] = bw[j * 4 + 0];
        stg[tid][1] = bw[j * 4 + 1];
        stg[tid][2] = bw[j * 4 + 2];
        stg[tid][3] = bw[j * 4 + 3];
        __syncthreads();
#pragma unroll
        for (int k = 0; k < 25; ++k) {
            const int idx = tid + k * 256;        // 0..6399
            const int u   = idx / 25;             // site 0..255
            const int tt  = (idx - u * 25) * 4;   // t0 of this float4 (4-aligned)
            const unsigned bs = stg[u][tt >> 5] >> (tt & 31);
            float4 v;
            v.x = (float)( bs        & 1u);
            v.y = (float)((bs >> 1)  & 1u);
            v.z = (float)((bs >> 2)  & 1u);
            v.w = (float)((bs >> 3)  & 1u);
            const int rr = u >> 4, cc = u & 15;
            *(float4*)(outb + (((size_t)co * HH + (h0 + rr)) * WW + (w0 + cc)) * TT + tt) = v;
        }
        __syncthreads();
    }
}

extern "C" void kernel_launch(void* const* d_in, const int* in_sizes, int n_in,
                              void* d_out, int out_size, void* d_ws, size_t ws_size,
                              hipStream_t stream) {
    const float* x      = (const float*)d_in[0];
    const float* wgt    = (const float*)d_in[1];
    const float* thresh = (const float*)d_in[2];
    float* out = (float*)d_out;
    (void)d_ws; (void)ws_size;

    dim3 grid(32 * 16 * 2);   // images x tiles x co-halves = 1024
    dim3 block(256);
    sconv2d_spike_kernel<<<grid, block, 0, stream>>>(x, wgt, thresh, out);
}

// Round 8
// 538.996 us; speedup vs baseline: 2.8149x; 2.6329x over previous
//
#include <hip/hip_runtime.h>

#define HH 64
#define WW 64
#define TT 100
#define CO 8
#define COB 4                      // couts per block (split across 2 blocks)
#define KS 6
#define LP 2
#define HALO 21                    // 16 + 6 - 1
#define NSITE 441                  // 21*21
#define NGMAX 7

typedef float f32x4 __attribute__((ext_vector_type(4)));

__device__ __forceinline__ float stepu(float u, float s, float th, float wx) {
    // u = (u - s*th) + wx  -- exact reference association, no contraction
    return __fadd_rn(__fsub_rn(u, __fmul_rn(s, th)), wx);
}

// Stage x[t0..t0+TC) halo into LDS, conv (kh-major sequential FMA, bit-exact
// vs np ref), scan; accumulate spike bits in registers (static indices only).
template<int T0, int TC>
__device__ __forceinline__ void process_chunk(
    const float* __restrict__ xb,
    float4* __restrict__ xs, const float (*wds)[CO],
    int tid, int r, int c, int h0, int w0, int co0, float th,
    float* ut, float* sprev, unsigned* bw /* COB*4 words, static idx */)
{
    constexpr int NG = TC / 4;

    for (int i = tid; i < NSITE * NG; i += 256) {
        const int s  = i / NG;
        const int tg = i - s * NG;
        const int hr = s / HALO;
        const int hc = s - hr * HALO;
        const int hh = h0 - LP + hr;
        const int ww = w0 - LP + hc;
        float4 v = make_float4(0.f, 0.f, 0.f, 0.f);
        if ((unsigned)hh < (unsigned)HH && (unsigned)ww < (unsigned)WW)
            v = *(const float4*)(xb + ((size_t)hh * WW + ww) * TT + T0 + tg * 4);
        xs[tg * NSITE + s] = v;
    }
    __syncthreads();

    unsigned cb[COB];
#pragma unroll
    for (int j = 0; j < COB; ++j) cb[j] = 0u;

    for (int tg = 0; tg < NG; ++tg) {
        float4 wx[COB];
#pragma unroll
        for (int j = 0; j < COB; ++j) wx[j] = make_float4(0.f, 0.f, 0.f, 0.f);
#pragma unroll
        for (int kh = 0; kh < KS; ++kh) {
#pragma unroll
            for (int kw = 0; kw < KS; ++kw) {
                const float4 xv = xs[tg * NSITE + (r + kh) * HALO + (c + kw)];
                const int tap = kh * KS + kw;
#pragma unroll
                for (int j = 0; j < COB; ++j) {
                    const float wd = wds[tap][co0 + j];
                    wx[j].x = __fmaf_rn(wd, xv.x, wx[j].x);
                    wx[j].y = __fmaf_rn(wd, xv.y, wx[j].y);
                    wx[j].z = __fmaf_rn(wd, xv.z, wx[j].z);
                    wx[j].w = __fmaf_rn(wd, xv.w, wx[j].w);
                }
            }
        }
        const int sh = tg * 4;
#pragma unroll
        for (int j = 0; j < COB; ++j) {
            float u = ut[j], s = sprev[j];
            unsigned m = 0u;
            u = stepu(u, s, th, wx[j].x); s = (u > 0.f) ? 1.f : 0.f; m |= (u > 0.f) ? 1u : 0u;
            u = stepu(u, s, th, wx[j].y); s = (u > 0.f) ? 1.f : 0.f; m |= (u > 0.f) ? 2u : 0u;
            u = stepu(u, s, th, wx[j].z); s = (u > 0.f) ? 1.f : 0.f; m |= (u > 0.f) ? 4u : 0u;
            u = stepu(u, s, th, wx[j].w); s = (u > 0.f) ? 1.f : 0.f; m |= (u > 0.f) ? 8u : 0u;
            ut[j] = u; sprev[j] = s;
            cb[j] |= m << sh;
        }
    }
    __syncthreads();   // compute done before next chunk overwrites xs

    constexpr int W0 = T0 / 32;
    constexpr int S  = T0 % 32;
#pragma unroll
    for (int j = 0; j < COB; ++j) {
        bw[j * 4 + W0] |= cb[j] << S;
        if constexpr (S + TC > 32)
            bw[j * 4 + W0 + 1] |= cb[j] >> ((32 - S) & 31);
    }
}

__global__ __launch_bounds__(256, 2)
void sconv2d_spike_kernel(const float* __restrict__ x,
                          const float* __restrict__ wgt,
                          const float* __restrict__ thresh,
                          float* __restrict__ out)
{
    __shared__ float4   xs[NGMAX * NSITE];    // 49.4 KB
    __shared__ float    wds[KS * KS][CO];     // 1.2 KB
    __shared__ unsigned stg[256][17];         // 17.4 KB (stride 17: conflict-free)
    // total 68 KB -> 2 blocks/CU, same residency as round-0 baseline

    const int tid = threadIdx.x;
    for (int i = tid; i < KS * KS * CO; i += 256) {
        const int co  = i / (KS * KS);
        const int tap = i - co * (KS * KS);
        wds[tap][co] = wgt[co * (KS * KS) + tap];
    }
    const float th = thresh[0];

    // grid = 32 images x 16 tiles x 2 co-halves
    const int blk  = blockIdx.x;
    const int b    = blk >> 5;
    const int rest = blk & 31;
    const int tb   = rest >> 1;
    const int co0  = (rest & 1) * COB;
    const int h0   = (tb >> 2) << 4;
    const int w0   = (tb & 3) << 4;
    const int r    = tid >> 4;
    const int c    = tid & 15;

    const float* xb   = x   + (size_t)b * (HH * WW * TT);
    float*       outb = out + (size_t)b * (CO * HH * WW * TT);

    float ut[COB], sprev[COB];
    unsigned bw[COB * 4];
#pragma unroll
    for (int j = 0; j < COB; ++j) { ut[j] = 0.f; sprev[j] = 0.f; }
#pragma unroll
    for (int i = 0; i < COB * 4; ++i) bw[i] = 0u;

    process_chunk< 0, 28>(xb, xs, wds, tid, r, c, h0, w0, co0, th, ut, sprev, bw);
    process_chunk<28, 28>(xb, xs, wds, tid, r, c, h0, w0, co0, th, ut, sprev, bw);
    process_chunk<56, 28>(xb, xs, wds, tid, r, c, h0, w0, co0, th, ut, sprev, bw);
    process_chunk<84, 16>(xb, xs, wds, tid, r, c, h0, w0, co0, th, ut, sprev, bw);

    // ---- flush (single pass): stage all 16 bit-words once, one barrier,
    //      then full-line coalesced NON-TEMPORAL float4 stores ----
#pragma unroll
    for (int w = 0; w < 16; ++w)
        stg[tid][w] = bw[w];
    __syncthreads();

#pragma unroll
    for (int j = 0; j < COB; ++j) {
        const int co = co0 + j;
#pragma unroll
        for (int k = 0; k < 25; ++k) {
            const int idx = tid + k * 256;        // 0..6399
            const int u   = idx / 25;             // site 0..255
            const int tt  = (idx - u * 25) * 4;   // t0 of this float4 (4-aligned)
            const unsigned bs = stg[u][j * 4 + (tt >> 5)] >> (tt & 31);
            f32x4 v;
            v.x = (float)( bs        & 1u);
            v.y = (float)((bs >> 1)  & 1u);
            v.z = (float)((bs >> 2)  & 1u);
            v.w = (float)((bs >> 3)  & 1u);
            const int rr = u >> 4, cc = u & 15;
            f32x4* dst = (f32x4*)(outb + (((size_t)co * HH + (h0 + rr)) * WW
                                          + (w0 + cc)) * TT + tt);
            __builtin_nontemporal_store(v, dst);   // write-once stream: skip L2/L3 pollution
        }
    }
}

extern "C" void kernel_launch(void* const* d_in, const int* in_sizes, int n_in,
                              void* d_out, int out_size, void* d_ws, size_t ws_size,
                              hipStream_t stream) {
    const float* x      = (const float*)d_in[0];
    const float* wgt    = (const float*)d_in[1];
    const float* thresh = (const float*)d_in[2];
    float* out = (float*)d_out;
    (void)d_ws; (void)ws_size;

    dim3 grid(32 * 16 * 2);   // images x tiles x co-halves = 1024
    dim3 block(256);
    sconv2d_spike_kernel<<<grid, block, 0, stream>>>(x, wgt, thresh, out);
}

// Round 9
// 536.036 us; speedup vs baseline: 2.8305x; 1.0055x over previous
//
#include <hip/hip_runtime.h>

#define HH 64
#define WW 64
#define TT 100
#define CO 8
#define COB 4                      // couts per block (split across 2 blocks)
#define KS 6
#define LP 2
#define HALO 21                    // 16 + 6 - 1
#define NSITE 441                  // 21*21
#define NGMAX 7

typedef float f32x4 __attribute__((ext_vector_type(4)));

__device__ __forceinline__ float stepu(float u, float s, float th, float wx) {
    // u = (u - s*th) + wx  -- exact reference association, no contraction
    return __fadd_rn(__fsub_rn(u, __fmul_rn(s, th)), wx);
}

// Stage x[t0..t0+TC) halo into LDS, conv (kh-major sequential FMA, bit-exact
// vs np ref), scan; accumulate spike bits in registers (static indices only).
template<int T0, int TC>
__device__ __forceinline__ void process_chunk(
    const float* __restrict__ xb,
    float4* __restrict__ xs, const float (*wds)[CO],
    int tid, int r, int c, int h0, int w0, int co0, float th,
    float* ut, float* sprev, unsigned* bw /* COB*4 words, static idx */)
{
    constexpr int NG = TC / 4;

    for (int i = tid; i < NSITE * NG; i += 256) {
        const int s  = i / NG;
        const int tg = i - s * NG;
        const int hr = s / HALO;
        const int hc = s - hr * HALO;
        const int hh = h0 - LP + hr;
        const int ww = w0 - LP + hc;
        float4 v = make_float4(0.f, 0.f, 0.f, 0.f);
        if ((unsigned)hh < (unsigned)HH && (unsigned)ww < (unsigned)WW)
            v = *(const float4*)(xb + ((size_t)hh * WW + ww) * TT + T0 + tg * 4);
        xs[tg * NSITE + s] = v;
    }
    __syncthreads();

    unsigned cb[COB];
#pragma unroll
    for (int j = 0; j < COB; ++j) cb[j] = 0u;

    for (int tg = 0; tg < NG; ++tg) {
        float4 wx[COB];
#pragma unroll
        for (int j = 0; j < COB; ++j) wx[j] = make_float4(0.f, 0.f, 0.f, 0.f);
#pragma unroll
        for (int kh = 0; kh < KS; ++kh) {
#pragma unroll
            for (int kw = 0; kw < KS; ++kw) {
                const float4 xv = xs[tg * NSITE + (r + kh) * HALO + (c + kw)];
                const int tap = kh * KS + kw;
#pragma unroll
                for (int j = 0; j < COB; ++j) {
                    const float wd = wds[tap][co0 + j];
                    wx[j].x = __fmaf_rn(wd, xv.x, wx[j].x);
                    wx[j].y = __fmaf_rn(wd, xv.y, wx[j].y);
                    wx[j].z = __fmaf_rn(wd, xv.z, wx[j].z);
                    wx[j].w = __fmaf_rn(wd, xv.w, wx[j].w);
                }
            }
        }
        const int sh = tg * 4;
#pragma unroll
        for (int j = 0; j < COB; ++j) {
            float u = ut[j], s = sprev[j];
            unsigned m = 0u;
            u = stepu(u, s, th, wx[j].x); s = (u > 0.f) ? 1.f : 0.f; m |= (u > 0.f) ? 1u : 0u;
            u = stepu(u, s, th, wx[j].y); s = (u > 0.f) ? 1.f : 0.f; m |= (u > 0.f) ? 2u : 0u;
            u = stepu(u, s, th, wx[j].z); s = (u > 0.f) ? 1.f : 0.f; m |= (u > 0.f) ? 4u : 0u;
            u = stepu(u, s, th, wx[j].w); s = (u > 0.f) ? 1.f : 0.f; m |= (u > 0.f) ? 8u : 0u;
            ut[j] = u; sprev[j] = s;
            cb[j] |= m << sh;
        }
    }
    __syncthreads();   // compute done before next chunk overwrites xs

    constexpr int W0 = T0 / 32;
    constexpr int S  = T0 % 32;
#pragma unroll
    for (int j = 0; j < COB; ++j) {
        bw[j * 4 + W0] |= cb[j] << S;
        if constexpr (S + TC > 32)
            bw[j * 4 + W0 + 1] |= cb[j] >> ((32 - S) & 31);
    }
}

__global__ __launch_bounds__(256, 2)
void sconv2d_spike_kernel(const float* __restrict__ x,
                          const float* __restrict__ wgt,
                          const float* __restrict__ thresh,
                          float* __restrict__ out)
{
    __shared__ float4   xs[NGMAX * NSITE];    // 49.4 KB
    __shared__ float    wds[KS * KS][CO];     // 1.2 KB
    __shared__ unsigned stg[256][17];         // 17.4 KB (stride 17: conflict-free)
    // total 68 KB -> 2 blocks/CU, same residency as round-0 baseline

    const int tid = threadIdx.x;
    for (int i = tid; i < KS * KS * CO; i += 256) {
        const int co  = i / (KS * KS);
        const int tap = i - co * (KS * KS);
        wds[tap][co] = wgt[co * (KS * KS) + tap];
    }
    const float th = thresh[0];

    // XCD-aware swizzle (entry-only, bijective: 1024 = 8 * 128).
    // HW assigns xcd ~ blockIdx % 8; remap so each XCD gets a CONTIGUOUS run
    // of 128 work-ids = 4 complete images -> per-chunk staging working set
    // ~1.8 MB, L2-resident; co-pair duplicate halo reads become L2 hits.
    const int blk  = ((blockIdx.x & 7) << 7) + (blockIdx.x >> 3);

    // work-id decode = 32 images x 16 tiles x 2 co-halves
    const int b    = blk >> 5;
    const int rest = blk & 31;
    const int tb   = rest >> 1;
    const int co0  = (rest & 1) * COB;
    const int h0   = (tb >> 2) << 4;
    const int w0   = (tb & 3) << 4;
    const int r    = tid >> 4;
    const int c    = tid & 15;

    const float* xb   = x   + (size_t)b * (HH * WW * TT);
    float*       outb = out + (size_t)b * (CO * HH * WW * TT);

    float ut[COB], sprev[COB];
    unsigned bw[COB * 4];
#pragma unroll
    for (int j = 0; j < COB; ++j) { ut[j] = 0.f; sprev[j] = 0.f; }
#pragma unroll
    for (int i = 0; i < COB * 4; ++i) bw[i] = 0u;

    process_chunk< 0, 28>(xb, xs, wds, tid, r, c, h0, w0, co0, th, ut, sprev, bw);
    process_chunk<28, 28>(xb, xs, wds, tid, r, c, h0, w0, co0, th, ut, sprev, bw);
    process_chunk<56, 28>(xb, xs, wds, tid, r, c, h0, w0, co0, th, ut, sprev, bw);
    process_chunk<84, 16>(xb, xs, wds, tid, r, c, h0, w0, co0, th, ut, sprev, bw);

    // ---- flush (single pass): stage all 16 bit-words once, one barrier,
    //      then full-line coalesced NON-TEMPORAL float4 stores ----
#pragma unroll
    for (int w = 0; w < 16; ++w)
        stg[tid][w] = bw[w];
    __syncthreads();

#pragma unroll
    for (int j = 0; j < COB; ++j) {
        const int co = co0 + j;
#pragma unroll
        for (int k = 0; k < 25; ++k) {
            const int idx = tid + k * 256;        // 0..6399
            const int u   = idx / 25;             // site 0..255
            const int tt  = (idx - u * 25) * 4;   // t0 of this float4 (4-aligned)
            const unsigned bs = stg[u][j * 4 + (tt >> 5)] >> (tt & 31);
            f32x4 v;
            v.x = (float)( bs        & 1u);
            v.y = (float)((bs >> 1)  & 1u);
            v.z = (float)((bs >> 2)  & 1u);
            v.w = (float)((bs >> 3)  & 1u);
            const int rr = u >> 4, cc = u & 15;
            f32x4* dst = (f32x4*)(outb + (((size_t)co * HH + (h0 + rr)) * WW
                                          + (w0 + cc)) * TT + tt);
            __builtin_nontemporal_store(v, dst);   // write-once stream: skip L2/L3 pollution
        }
    }
}

extern "C" void kernel_launch(void* const* d_in, const int* in_sizes, int n_in,
                              void* d_out, int out_size, void* d_ws, size_t ws_size,
                              hipStream_t stream) {
    const float* x      = (const float*)d_in[0];
    const float* wgt    = (const float*)d_in[1];
    const float* thresh = (const float*)d_in[2];
    float* out = (float*)d_out;
    (void)d_ws; (void)ws_size;

    dim3 grid(32 * 16 * 2);   // images x tiles x co-halves = 1024
    dim3 block(256);
    sconv2d_spike_kernel<<<grid, block, 0, stream>>>(x, wgt, thresh, out);
}